// Round 9
// baseline (485.673 us; speedup 1.0000x reference)
//
#include <hip/hip_runtime.h>
#include <hip/hip_bf16.h>

typedef __attribute__((ext_vector_type(8))) short bf16x8;
typedef __attribute__((ext_vector_type(4))) float f32x4;
typedef __attribute__((ext_vector_type(4))) unsigned int u32x4;

// ---------------- bf16 helpers ----------------
__device__ __forceinline__ unsigned short f2bf(float f) {
  __hip_bfloat16 h = __float2bfloat16(f);
  return __builtin_bit_cast(unsigned short, h);
}

// ---------------- init: Wigner 3j coefficients + weight transpose ----------------
struct cplx { double re, im; };
__device__ __forceinline__ cplx cmul(cplx a, cplx b) {
  return {a.re * b.re - a.im * b.im, a.re * b.im + a.im * b.re};
}
__device__ __forceinline__ double fct_(int n) {
  const double f[8] = {1., 1., 2., 6., 24., 120., 720., 5040.};
  return f[n];
}
__device__ __forceinline__ int imax_(int a, int b) { return a > b ? a : b; }
__device__ __forceinline__ int imin_(int a, int b) { return a < b ? a : b; }

__device__ double su2_cg(int j1, int j2, int j3, int m1, int m2, int m3) {
  if (m3 != m1 + m2) return 0.0;
  int vmin = imax_(imax_(-j1 + j2 + m3, -j1 + m1), 0);
  int vmax = imin_(imin_(j2 + j3 + m1, j3 - j1 + j2), j3 + m3);
  double C = sqrt((2.0 * j3 + 1.0) * fct_(j3 + j1 - j2) * fct_(j3 - j1 + j2) * fct_(j1 + j2 - j3)
                  * fct_(j3 + m3) * fct_(j3 - m3)
                  / (fct_(j1 + j2 + j3 + 1) * fct_(j1 - m1) * fct_(j1 + m1) * fct_(j2 - m2) * fct_(j2 + m2)));
  double S = 0.0;
  for (int v = vmin; v <= vmax; ++v) {
    double sgn = ((v + j2 + m2) & 1) ? -1.0 : 1.0;
    S += sgn * fct_(j2 + j3 + m1 - v) * fct_(j1 - m1 + v)
         / (fct_(v) * fct_(j3 - j1 + j2 - v) * fct_(j3 + m3 - v) * fct_(v + j1 - j2 - m3));
  }
  return C * S;
}

__device__ cplx q_entry(int l, int r, int c) {
  const double s2 = 0.70710678118654752440;
  int m = r - l;
  cplx v = {0.0, 0.0};
  if (m < 0) {
    if (c == l - m) v = {s2, 0.0};
    else if (c == l + m) v = {0.0, -s2};
  } else if (m == 0) {
    if (c == l) v = {1.0, 0.0};
  } else {
    double sgn = (m & 1) ? -1.0 : 1.0;
    if (c == l + m) v = {sgn * s2, 0.0};
    else if (c == l - m) v = {0.0, sgn * s2};
  }
  cplx f;
  switch (l & 3) {
    case 0: f = {1.0, 0.0}; break;
    case 1: f = {0.0, -1.0}; break;
    case 2: f = {-1.0, 0.0}; break;
    default: f = {0.0, 1.0}; break;
  }
  return cmul(f, v);
}

// blocks 0..703: transpose weights fp32 [p][u][w] -> bf16 [p][w][u]
// blocks 704..714: Wigner 3j * path-normalization into cgw[p*125 + i*25 + j*5 + k]
// block 715: pack g-metadata GMAP[e] for the 115 (p,i,k) fold entries
__global__ void init_kernel(const float* __restrict__ w, unsigned short* __restrict__ Wt,
                            float* __restrict__ cgw, unsigned int* __restrict__ gmap) {
  const int blk = blockIdx.x;
  const int tid = threadIdx.x;
  if (blk < 704) {
    int g = blk * 256 + tid;                 // 704*256 == 180224 exactly
    int p = g >> 14, rem = g & 16383;
    int u = rem >> 7, wc = rem & 127;
    Wt[(p << 14) + (wc << 7) + u] = f2bf(w[g]);
    return;
  }
  if (blk == 715) {
    if (tid < 115) {
      const int PBt[12] = {0,1,4,9,18,21,36,45,70,85,90,115};
      const int D2t[11] = {1,3,5,1,3,3,5,1,3,5,5};
      const int D3t[11] = {1,3,5,3,1,5,3,5,3,1,5};
      const int O2t[11] = {0,1,4,0,1,1,4,0,1,4,4};
      int p = 0;
      while (tid >= PBt[p + 1]) ++p;
      int le = tid - PBt[p];
      int i = le / D3t[p], k = le % D3t[p];
      gmap[tid] = ((unsigned)(p * 125 + i * 25 + k) << 8) | (O2t[p] << 4) | D2t[p];
    }
    return;
  }
  const int p = blk - 704;
  const int L1t[11] = {0,0,0,1,1,1,1,2,2,2,2};
  const int L2t[11] = {0,1,2,0,1,1,2,0,1,2,2};
  const int L3t[11] = {0,1,2,1,0,2,1,2,1,0,2};
  const double FAN[11] = {384.,512.,512.,512.,384.,512.,512.,512.,512.,384.,512.};
  const int l1 = L1t[p], l2 = L2t[p], l3 = L3t[p];
  const int n1 = 2 * l1 + 1, n2 = 2 * l2 + 1, n3 = 2 * l3 + 1;
  if (tid >= n1 * n2 * n3) return;
  const int a = tid / (n2 * n3), b = (tid / n3) % n2, c = tid % n3;
  double sre = 0.0;
  for (int i = 0; i < n1; ++i)
    for (int k = 0; k < n2; ++k)
      for (int n = 0; n < n3; ++n) {
        double cg = su2_cg(l1, l2, l3, i - l1, k - l2, n - l3);
        if (cg == 0.0) continue;
        cplx q1 = q_entry(l1, i, a);
        cplx q2 = q_entry(l2, k, b);
        cplx q3 = q_entry(l3, n, c);
        q3.im = -q3.im;                      // conj(Q3)
        cplx pr = cmul(cmul(q1, q2), q3);
        sre += pr.re * cg;
      }
  cgw[p * 125 + a * 25 + b * 5 + c] = (float)(sre / sqrt(FAN[p]));
}

// ---------------- main kernel ----------------
// LDS x1 tile: PLANE-MAJOR bf16. 9 planes (l1=0: 1, l1=1: 3, l1=2: 5), each
// 16 rows x 128 u at pitch 132 shorts (264B rows -> 4-way-max bank pattern).
// Plane pi base = pi*2112 shorts. Total 19008 shorts = 38016 B.
// g_lds[e][row16] f32: 115 fold entries x 16 rows = 7360 B.
__device__ __forceinline__ void stage_all(const float* __restrict__ x1, int Mbase,
                                          unsigned short* __restrict__ s_a) {
  const int tid = threadIdx.x;
#pragma unroll 4
  for (int rep = 0; rep < 18; ++rep) {
    int it = tid + rep * 256;                // 4608 float4-loads total
    int row = it / 288, c4 = it % 288;
    int col = c4 << 2;                       // float4 never straddles groups
    const f32x4 v = __builtin_nontemporal_load(
        (const f32x4*)&x1[(size_t)(Mbase + row) * 1152 + col]);
    unsigned short* sr = s_a + row * 132;
    if (col < 128) {
#pragma unroll
      for (int q = 0; q < 4; ++q) sr[col + q] = f2bf(v[q]);
    } else if (col < 512) {
      int cc = col - 128;
#pragma unroll
      for (int q = 0; q < 4; ++q) {
        int u = (cc + q) / 3, i = (cc + q) % 3;
        sr[(1 + i) * 2112 + u] = f2bf(v[q]);
      }
    } else {
      int cc = col - 512;
#pragma unroll
      for (int q = 0; q < 4; ++q) {
        int u = (cc + q) / 5, i = (cc + q) % 5;
        sr[(4 + i) * 2112 + u] = f2bf(v[q]);
      }
    }
  }
}

// y_p[b,i,w] = sum_u x1[b,u,i] * W_p[u,w]  (MFMA GEMM per component i),
// then fold: acc[k] += g[b,i,k] * y[i]  (g from LDS, broadcast reads).
template<int PID, int L1, int L3, int PBASE>
__device__ __forceinline__ void do_path(const unsigned short* __restrict__ s_a,
                                        const float* __restrict__ g_lds,
                                        const unsigned short* __restrict__ Wt,
                                        int kg, int r16, int nbase,
                                        f32x4 (&acc)[2 * L3 + 1][2]) {
  constexpr int D1 = 2 * L1 + 1, D3 = 2 * L3 + 1;
  constexpr int GB = (L1 == 0) ? 0 : ((L1 == 1) ? 2112 : 8448);
  f32x4 y[D1][2];
#pragma unroll
  for (int i = 0; i < D1; ++i)
#pragma unroll
    for (int nf = 0; nf < 2; ++nf) y[i][nf] = f32x4{0.f, 0.f, 0.f, 0.f};
  const unsigned short* __restrict__ wbase = Wt + (PID << 14);
  // unroll 1: cap transient live ranges (af/bw) per iteration (R6 lesson).
#pragma unroll 1
  for (int us = 0; us < 4; ++us) {
    const int u0 = us * 32 + kg * 8;
    const unsigned short* ap = s_a + GB + r16 * 132 + u0;
    u32x4 af[D1];
#pragma unroll
    for (int d = 0; d < D1; ++d) af[d] = *(const u32x4*)(ap + d * 2112);
    u32x4 bw[2];
#pragma unroll
    for (int nf = 0; nf < 2; ++nf)
      bw[nf] = *(const u32x4*)&wbase[(nbase + nf * 16 + r16) * 128 + u0];
#pragma unroll
    for (int i = 0; i < D1; ++i)
#pragma unroll
      for (int nf = 0; nf < 2; ++nf)
        y[i][nf] = __builtin_amdgcn_mfma_f32_16x16x32_bf16(
            __builtin_bit_cast(bf16x8, af[i]), __builtin_bit_cast(bf16x8, bw[nf]),
            y[i][nf], 0, 0, 0);
  }
  // fold via g from LDS: g4 = g[e][kg*4 .. kg*4+3] (rows of this lane's accs)
#pragma unroll
  for (int i = 0; i < D1; ++i)
#pragma unroll
    for (int k = 0; k < D3; ++k) {
      const f32x4 g4 = *(const f32x4*)&g_lds[((PBASE + i * D3 + k) << 4) + (kg << 2)];
#pragma unroll
      for (int nf = 0; nf < 2; ++nf) acc[k][nf] += g4 * y[i][nf];
    }
}

__global__ void __launch_bounds__(256, 2) fctp_main(
    const float* __restrict__ x1, const float* __restrict__ x2,
    const float* __restrict__ cgw, const unsigned int* __restrict__ gmap,
    const unsigned short* __restrict__ Wt, float* __restrict__ out) {
  __shared__ __align__(16) unsigned short s_a[19008];  // 38016 B plane-major x1
  __shared__ __align__(16) float g_lds[1840];          // 7360 B g[e][row]
  const int tid = threadIdx.x;
  const int Mbase = blockIdx.x << 4;

  stage_all(x1, Mbase, s_a);

  // cooperative g: g[e][row] = sum_j x2[Mbase+row][o2+j] * cgw[co + j*5]
#pragma unroll 1
  for (int t = tid; t < 1840; t += 256) {
    int row = t & 15, e = t >> 4;
    unsigned m = gmap[e];
    int d2 = m & 15, o2 = (m >> 4) & 15, co = m >> 8;
    const float* xp = x2 + (size_t)(Mbase + row) * 9 + o2;
    const float* cp = cgw + co;
    float s = 0.f;
    for (int j = 0; j < d2; ++j) s += xp[j] * cp[j * 5];
    g_lds[(e << 4) + row] = s;
  }

  const int lane = tid & 63, ni = tid >> 6;
  const int r16 = lane & 15, kg = lane >> 4;
  const int nbase = ni << 5;          // this wave's 32-wide w window

  __syncthreads();                    // x1 planes + g ready

  const int bout = Mbase + (kg << 2);

  // ---- i3 = 0 (cols [0,128), d3=1): paths 0,4,9 ----
  {
    f32x4 acc[1][2] = {};
    do_path<0, 0, 0, 0>(s_a, g_lds, Wt, kg, r16, nbase, acc);
    do_path<4, 1, 0, 18>(s_a, g_lds, Wt, kg, r16, nbase, acc);
    do_path<9, 2, 0, 85>(s_a, g_lds, Wt, kg, r16, nbase, acc);
#pragma unroll
    for (int nf = 0; nf < 2; ++nf) {
      const int w = nbase + nf * 16 + r16;
#pragma unroll
      for (int r = 0; r < 4; ++r)
        __builtin_nontemporal_store(acc[0][nf][r],
                                    &out[(size_t)(bout + r) * 1152 + w]);
    }
  }
  // ---- i3 = 1 (cols 128 + w*3 + k, d3=3): paths 1,3,6,8 ----
  {
    f32x4 acc[3][2] = {};
    do_path<1, 0, 1, 1>(s_a, g_lds, Wt, kg, r16, nbase, acc);
    do_path<3, 1, 1, 9>(s_a, g_lds, Wt, kg, r16, nbase, acc);
    do_path<6, 1, 1, 36>(s_a, g_lds, Wt, kg, r16, nbase, acc);
    do_path<8, 2, 1, 70>(s_a, g_lds, Wt, kg, r16, nbase, acc);
#pragma unroll
    for (int nf = 0; nf < 2; ++nf) {
      const int w = nbase + nf * 16 + r16;
#pragma unroll
      for (int r = 0; r < 4; ++r) {
        float* o = out + (size_t)(bout + r) * 1152 + 128 + w * 3;
#pragma unroll
        for (int k = 0; k < 3; ++k) o[k] = acc[k][nf][r];
      }
    }
  }
  // ---- i3 = 2 (cols 512 + w*5 + k, d3=5): paths 2,5,7,10 ----
  {
    f32x4 acc[5][2] = {};
    do_path<2, 0, 2, 4>(s_a, g_lds, Wt, kg, r16, nbase, acc);
    do_path<5, 1, 2, 21>(s_a, g_lds, Wt, kg, r16, nbase, acc);
    do_path<7, 2, 2, 45>(s_a, g_lds, Wt, kg, r16, nbase, acc);
    do_path<10, 2, 2, 90>(s_a, g_lds, Wt, kg, r16, nbase, acc);
#pragma unroll
    for (int nf = 0; nf < 2; ++nf) {
      const int w = nbase + nf * 16 + r16;
#pragma unroll
      for (int r = 0; r < 4; ++r) {
        float* o = out + (size_t)(bout + r) * 1152 + 512 + w * 5;
#pragma unroll
        for (int k = 0; k < 5; ++k) o[k] = acc[k][nf][r];
      }
    }
  }
}

extern "C" void kernel_launch(void* const* d_in, const int* in_sizes, int n_in,
                              void* d_out, int out_size, void* d_ws, size_t ws_size,
                              hipStream_t stream) {
  (void)in_sizes; (void)n_in; (void)out_size; (void)ws_size;
  const float* x1 = (const float*)d_in[0];
  const float* x2 = (const float*)d_in[1];
  const float* w  = (const float*)d_in[2];
  float* out = (float*)d_out;
  float* cgw = (float*)d_ws;                                     // 1375 floats
  unsigned int* gmap = (unsigned int*)((char*)d_ws + 5504);      // 115 u32
  unsigned short* Wt = (unsigned short*)((char*)d_ws + 8192);    // 11*128*128 bf16
  init_kernel<<<dim3(716), dim3(256), 0, stream>>>(w, Wt, cgw, gmap);
  fctp_main<<<dim3(4096), dim3(256), 0, stream>>>(x1, x2, cgw, gmap, Wt, out);
}

// Round 10
// 390.433 us; speedup vs baseline: 1.2439x; 1.2439x over previous
//
#include <hip/hip_runtime.h>
#include <hip/hip_bf16.h>

typedef __attribute__((ext_vector_type(8))) short bf16x8;
typedef __attribute__((ext_vector_type(4))) float f32x4;
typedef __attribute__((ext_vector_type(4))) unsigned int u32x4;
typedef __attribute__((ext_vector_type(4))) unsigned short u16x4;

// ---------------- bf16 helpers ----------------
__device__ __forceinline__ unsigned short f2bf(float f) {
  __hip_bfloat16 h = __float2bfloat16(f);
  return __builtin_bit_cast(unsigned short, h);
}

// ---------------- init: Wigner 3j coefficients + weight transpose ----------------
struct cplx { double re, im; };
__device__ __forceinline__ cplx cmul(cplx a, cplx b) {
  return {a.re * b.re - a.im * b.im, a.re * b.im + a.im * b.re};
}
__device__ __forceinline__ double fct_(int n) {
  const double f[8] = {1., 1., 2., 6., 24., 120., 720., 5040.};
  return f[n];
}
__device__ __forceinline__ int imax_(int a, int b) { return a > b ? a : b; }
__device__ __forceinline__ int imin_(int a, int b) { return a < b ? a : b; }

__device__ double su2_cg(int j1, int j2, int j3, int m1, int m2, int m3) {
  if (m3 != m1 + m2) return 0.0;
  int vmin = imax_(imax_(-j1 + j2 + m3, -j1 + m1), 0);
  int vmax = imin_(imin_(j2 + j3 + m1, j3 - j1 + j2), j3 + m3);
  double C = sqrt((2.0 * j3 + 1.0) * fct_(j3 + j1 - j2) * fct_(j3 - j1 + j2) * fct_(j1 + j2 - j3)
                  * fct_(j3 + m3) * fct_(j3 - m3)
                  / (fct_(j1 + j2 + j3 + 1) * fct_(j1 - m1) * fct_(j1 + m1) * fct_(j2 - m2) * fct_(j2 + m2)));
  double S = 0.0;
  for (int v = vmin; v <= vmax; ++v) {
    double sgn = ((v + j2 + m2) & 1) ? -1.0 : 1.0;
    S += sgn * fct_(j2 + j3 + m1 - v) * fct_(j1 - m1 + v)
         / (fct_(v) * fct_(j3 - j1 + j2 - v) * fct_(j3 + m3 - v) * fct_(v + j1 - j2 - m3));
  }
  return C * S;
}

__device__ cplx q_entry(int l, int r, int c) {
  const double s2 = 0.70710678118654752440;
  int m = r - l;
  cplx v = {0.0, 0.0};
  if (m < 0) {
    if (c == l - m) v = {s2, 0.0};
    else if (c == l + m) v = {0.0, -s2};
  } else if (m == 0) {
    if (c == l) v = {1.0, 0.0};
  } else {
    double sgn = (m & 1) ? -1.0 : 1.0;
    if (c == l + m) v = {sgn * s2, 0.0};
    else if (c == l - m) v = {0.0, sgn * s2};
  }
  cplx f;
  switch (l & 3) {
    case 0: f = {1.0, 0.0}; break;
    case 1: f = {0.0, -1.0}; break;
    case 2: f = {-1.0, 0.0}; break;
    default: f = {0.0, 1.0}; break;
  }
  return cmul(f, v);
}

// blocks 0..703: transpose weights fp32 [p][u][w] -> bf16 [p][w][u]
// blocks 704..714: Wigner 3j * path-normalization into cgw[p*125 + i*25 + j*5 + k]
// block 715: pack g-metadata GMAP[e] for the 115 (p,i,k) fold entries
__global__ void init_kernel(const float* __restrict__ w, unsigned short* __restrict__ Wt,
                            float* __restrict__ cgw, unsigned int* __restrict__ gmap) {
  const int blk = blockIdx.x;
  const int tid = threadIdx.x;
  if (blk < 704) {
    int g = blk * 256 + tid;                 // 704*256 == 180224 exactly
    int p = g >> 14, rem = g & 16383;
    int u = rem >> 7, wc = rem & 127;
    Wt[(p << 14) + (wc << 7) + u] = f2bf(w[g]);
    return;
  }
  if (blk == 715) {
    if (tid < 115) {
      const int PBt[12] = {0,1,4,9,18,21,36,45,70,85,90,115};
      const int D2t[11] = {1,3,5,1,3,3,5,1,3,5,5};
      const int D3t[11] = {1,3,5,3,1,5,3,5,3,1,5};
      const int O2t[11] = {0,1,4,0,1,1,4,0,1,4,4};
      int p = 0;
      while (tid >= PBt[p + 1]) ++p;
      int le = tid - PBt[p];
      int i = le / D3t[p], k = le % D3t[p];
      gmap[tid] = ((unsigned)(p * 125 + i * 25 + k) << 8) | (O2t[p] << 4) | D2t[p];
    }
    return;
  }
  const int p = blk - 704;
  const int L1t[11] = {0,0,0,1,1,1,1,2,2,2,2};
  const int L2t[11] = {0,1,2,0,1,1,2,0,1,2,2};
  const int L3t[11] = {0,1,2,1,0,2,1,2,1,0,2};
  const double FAN[11] = {384.,512.,512.,512.,384.,512.,512.,512.,512.,384.,512.};
  const int l1 = L1t[p], l2 = L2t[p], l3 = L3t[p];
  const int n1 = 2 * l1 + 1, n2 = 2 * l2 + 1, n3 = 2 * l3 + 1;
  if (tid >= n1 * n2 * n3) return;
  const int a = tid / (n2 * n3), b = (tid / n3) % n2, c = tid % n3;
  double sre = 0.0;
  for (int i = 0; i < n1; ++i)
    for (int k = 0; k < n2; ++k)
      for (int n = 0; n < n3; ++n) {
        double cg = su2_cg(l1, l2, l3, i - l1, k - l2, n - l3);
        if (cg == 0.0) continue;
        cplx q1 = q_entry(l1, i, a);
        cplx q2 = q_entry(l2, k, b);
        cplx q3 = q_entry(l3, n, c);
        q3.im = -q3.im;                      // conj(Q3)
        cplx pr = cmul(cmul(q1, q2), q3);
        sre += pr.re * cg;
      }
  cgw[p * 125 + a * 25 + b * 5 + c] = (float)(sre / sqrt(FAN[p]));
}

// ---------------- main kernel ----------------
// LDS x1 tile: PLANE-MAJOR bf16. 9 planes (l1=0: 1, l1=1: 3, l1=2: 5), each
// 16 rows x 128 u at pitch 132 shorts. Plane pi base = pi*2112 shorts.
// Total 19008 shorts = 38016 B. g_lds[e][row16] f32: 115 x 16 = 7360 B.
__device__ __forceinline__ void stage_all(const float* __restrict__ x1, int Mbase,
                                          unsigned short* __restrict__ s_a) {
  const int tid = threadIdx.x;
#pragma unroll 4
  for (int rep = 0; rep < 18; ++rep) {
    int it = tid + rep * 256;                // 4608 float4-loads total
    int row = it / 288, c4 = it % 288;
    int col = c4 << 2;                       // float4 never straddles groups
    const f32x4 v = __builtin_nontemporal_load(
        (const f32x4*)&x1[(size_t)(Mbase + row) * 1152 + col]);
    unsigned short* sr = s_a + row * 132;
    if (col < 128) {
      u16x4 h;
#pragma unroll
      for (int q = 0; q < 4; ++q) h[q] = f2bf(v[q]);
      *(u16x4*)&sr[col] = h;
    } else if (col < 512) {
      int cc = col - 128;
#pragma unroll
      for (int q = 0; q < 4; ++q) {
        int u = (cc + q) / 3, i = (cc + q) % 3;
        sr[(1 + i) * 2112 + u] = f2bf(v[q]);
      }
    } else {
      int cc = col - 512;
#pragma unroll
      for (int q = 0; q < 4; ++q) {
        int u = (cc + q) / 5, i = (cc + q) % 5;
        sr[(4 + i) * 2112 + u] = f2bf(v[q]);
      }
    }
  }
}

// y_p[b,i,w] = sum_u x1[b,u,i] * W_p[u,w]  (MFMA GEMM per component i), then
// fold acc[k] += g[b,i,k] * y_i immediately. i-outer/unroll-1 + hoisted
// bw[2][4] keeps peak live ~105 regs (R9 kept y[D1][2]+acc live = spills).
template<int PID, int L1, int L3, int PBASE>
__device__ __forceinline__ void do_path(const unsigned short* __restrict__ s_a,
                                        const float* __restrict__ g_lds,
                                        const unsigned short* __restrict__ Wt,
                                        int kg, int r16, int nbase,
                                        f32x4 (&acc)[2 * L3 + 1][2]) {
  constexpr int D1 = 2 * L1 + 1, D3 = 2 * L3 + 1;
  constexpr int GB = (L1 == 0) ? 0 : ((L1 == 1) ? 2112 : 8448);
  const unsigned short* __restrict__ wbase = Wt + (PID << 14);
  // all 8 weight frags once per path (32 VGPRs, same L2 traffic as before)
  u32x4 bw[2][4];
#pragma unroll
  for (int nf = 0; nf < 2; ++nf)
#pragma unroll
    for (int us = 0; us < 4; ++us)
      bw[nf][us] = *(const u32x4*)&wbase[(nbase + nf * 16 + r16) * 128 + us * 32 + kg * 8];
  const unsigned short* __restrict__ ap0 = s_a + GB + r16 * 132 + kg * 8;
#pragma unroll 1
  for (int i = 0; i < D1; ++i) {
    f32x4 y[2] = {f32x4{0.f, 0.f, 0.f, 0.f}, f32x4{0.f, 0.f, 0.f, 0.f}};
    const unsigned short* ap = ap0 + i * 2112;
#pragma unroll
    for (int us = 0; us < 4; ++us) {
      const u32x4 af = *(const u32x4*)(ap + us * 32);
#pragma unroll
      for (int nf = 0; nf < 2; ++nf)
        y[nf] = __builtin_amdgcn_mfma_f32_16x16x32_bf16(
            __builtin_bit_cast(bf16x8, af), __builtin_bit_cast(bf16x8, bw[nf][us]),
            y[nf], 0, 0, 0);
    }
#pragma unroll
    for (int k = 0; k < D3; ++k) {
      const f32x4 g4 = *(const f32x4*)&g_lds[((PBASE + i * D3 + k) << 4) + (kg << 2)];
#pragma unroll
      for (int nf = 0; nf < 2; ++nf) acc[k][nf] += g4 * y[nf];
    }
  }
}

__global__ void __launch_bounds__(256, 2) fctp_main(
    const float* __restrict__ x1, const float* __restrict__ x2,
    const float* __restrict__ cgw, const unsigned int* __restrict__ gmap,
    const unsigned short* __restrict__ Wt, float* __restrict__ out) {
  __shared__ __align__(16) unsigned short s_a[19008];  // 38016 B plane-major x1
  __shared__ __align__(16) float g_lds[1840];          // 7360 B g[e][row]
  const int tid = threadIdx.x;
  const int Mbase = blockIdx.x << 4;

  stage_all(x1, Mbase, s_a);

  // cooperative g: g[e][row] = sum_j x2[Mbase+row][o2+j] * cgw[co + j*5]
#pragma unroll 1
  for (int t = tid; t < 1840; t += 256) {
    int row = t & 15, e = t >> 4;
    unsigned m = gmap[e];
    int d2 = m & 15, o2 = (m >> 4) & 15, co = m >> 8;
    const float* xp = x2 + (size_t)(Mbase + row) * 9 + o2;
    const float* cp = cgw + co;
    float s = 0.f;
    for (int j = 0; j < d2; ++j) s += xp[j] * cp[j * 5];
    g_lds[(e << 4) + row] = s;
  }

  const int lane = tid & 63, ni = tid >> 6;
  const int r16 = lane & 15, kg = lane >> 4;
  const int nbase = ni << 5;          // this wave's 32-wide w window

  __syncthreads();                    // x1 planes + g ready

  const int bout = Mbase + (kg << 2);

  // ---- i3 = 0 (cols [0,128), d3=1): paths 0,4,9 ----
  {
    f32x4 acc[1][2] = {};
    do_path<0, 0, 0, 0>(s_a, g_lds, Wt, kg, r16, nbase, acc);
    do_path<4, 1, 0, 18>(s_a, g_lds, Wt, kg, r16, nbase, acc);
    do_path<9, 2, 0, 85>(s_a, g_lds, Wt, kg, r16, nbase, acc);
#pragma unroll
    for (int nf = 0; nf < 2; ++nf) {
      const int w = nbase + nf * 16 + r16;
#pragma unroll
      for (int r = 0; r < 4; ++r)
        __builtin_nontemporal_store(acc[0][nf][r],
                                    &out[(size_t)(bout + r) * 1152 + w]);
    }
  }
  // ---- i3 = 1 (cols 128 + w*3 + k, d3=3): paths 1,3,6,8 ----
  {
    f32x4 acc[3][2] = {};
    do_path<1, 0, 1, 1>(s_a, g_lds, Wt, kg, r16, nbase, acc);
    do_path<3, 1, 1, 9>(s_a, g_lds, Wt, kg, r16, nbase, acc);
    do_path<6, 1, 1, 36>(s_a, g_lds, Wt, kg, r16, nbase, acc);
    do_path<8, 2, 1, 70>(s_a, g_lds, Wt, kg, r16, nbase, acc);
#pragma unroll
    for (int nf = 0; nf < 2; ++nf) {
      const int w = nbase + nf * 16 + r16;
#pragma unroll
      for (int r = 0; r < 4; ++r) {
        float* o = out + (size_t)(bout + r) * 1152 + 128 + w * 3;
#pragma unroll
        for (int k = 0; k < 3; ++k) o[k] = acc[k][nf][r];
      }
    }
  }
  // ---- i3 = 2 (cols 512 + w*5 + k, d3=5): paths 2,5,7,10 ----
  {
    f32x4 acc[5][2] = {};
    do_path<2, 0, 2, 4>(s_a, g_lds, Wt, kg, r16, nbase, acc);
    do_path<5, 1, 2, 21>(s_a, g_lds, Wt, kg, r16, nbase, acc);
    do_path<7, 2, 2, 45>(s_a, g_lds, Wt, kg, r16, nbase, acc);
    do_path<10, 2, 2, 90>(s_a, g_lds, Wt, kg, r16, nbase, acc);
#pragma unroll
    for (int nf = 0; nf < 2; ++nf) {
      const int w = nbase + nf * 16 + r16;
#pragma unroll
      for (int r = 0; r < 4; ++r) {
        float* o = out + (size_t)(bout + r) * 1152 + 512 + w * 5;
#pragma unroll
        for (int k = 0; k < 5; ++k) o[k] = acc[k][nf][r];
      }
    }
  }
}

extern "C" void kernel_launch(void* const* d_in, const int* in_sizes, int n_in,
                              void* d_out, int out_size, void* d_ws, size_t ws_size,
                              hipStream_t stream) {
  (void)in_sizes; (void)n_in; (void)out_size; (void)ws_size;
  const float* x1 = (const float*)d_in[0];
  const float* x2 = (const float*)d_in[1];
  const float* w  = (const float*)d_in[2];
  float* out = (float*)d_out;
  float* cgw = (float*)d_ws;                                     // 1375 floats
  unsigned int* gmap = (unsigned int*)((char*)d_ws + 5504);      // 115 u32
  unsigned short* Wt = (unsigned short*)((char*)d_ws + 8192);    // 11*128*128 bf16
  init_kernel<<<dim3(716), dim3(256), 0, stream>>>(w, Wt, cgw, gmap);
  fctp_main<<<dim3(4096), dim3(256), 0, stream>>>(x1, x2, cgw, gmap, Wt, out);
}

// Round 11
// 370.860 us; speedup vs baseline: 1.3096x; 1.0528x over previous
//
#include <hip/hip_runtime.h>
#include <hip/hip_bf16.h>

typedef __attribute__((ext_vector_type(8))) short bf16x8;
typedef __attribute__((ext_vector_type(4))) float f32x4;
typedef __attribute__((ext_vector_type(4))) unsigned int u32x4;
typedef __attribute__((ext_vector_type(4))) unsigned short u16x4;

// ---------------- bf16 helpers ----------------
__device__ __forceinline__ unsigned short f2bf(float f) {
  __hip_bfloat16 h = __float2bfloat16(f);
  return __builtin_bit_cast(unsigned short, h);
}

// ---------------- init: Wigner 3j coefficients + weight transpose ----------------
struct cplx { double re, im; };
__device__ __forceinline__ cplx cmul(cplx a, cplx b) {
  return {a.re * b.re - a.im * b.im, a.re * b.im + a.im * b.re};
}
__device__ __forceinline__ double fct_(int n) {
  const double f[8] = {1., 1., 2., 6., 24., 120., 720., 5040.};
  return f[n];
}
__device__ __forceinline__ int imax_(int a, int b) { return a > b ? a : b; }
__device__ __forceinline__ int imin_(int a, int b) { return a < b ? a : b; }

__device__ double su2_cg(int j1, int j2, int j3, int m1, int m2, int m3) {
  if (m3 != m1 + m2) return 0.0;
  int vmin = imax_(imax_(-j1 + j2 + m3, -j1 + m1), 0);
  int vmax = imin_(imin_(j2 + j3 + m1, j3 - j1 + j2), j3 + m3);
  double C = sqrt((2.0 * j3 + 1.0) * fct_(j3 + j1 - j2) * fct_(j3 - j1 + j2) * fct_(j1 + j2 - j3)
                  * fct_(j3 + m3) * fct_(j3 - m3)
                  / (fct_(j1 + j2 + j3 + 1) * fct_(j1 - m1) * fct_(j1 + m1) * fct_(j2 - m2) * fct_(j2 + m2)));
  double S = 0.0;
  for (int v = vmin; v <= vmax; ++v) {
    double sgn = ((v + j2 + m2) & 1) ? -1.0 : 1.0;
    S += sgn * fct_(j2 + j3 + m1 - v) * fct_(j1 - m1 + v)
         / (fct_(v) * fct_(j3 - j1 + j2 - v) * fct_(j3 + m3 - v) * fct_(v + j1 - j2 - m3));
  }
  return C * S;
}

__device__ cplx q_entry(int l, int r, int c) {
  const double s2 = 0.70710678118654752440;
  int m = r - l;
  cplx v = {0.0, 0.0};
  if (m < 0) {
    if (c == l - m) v = {s2, 0.0};
    else if (c == l + m) v = {0.0, -s2};
  } else if (m == 0) {
    if (c == l) v = {1.0, 0.0};
  } else {
    double sgn = (m & 1) ? -1.0 : 1.0;
    if (c == l + m) v = {sgn * s2, 0.0};
    else if (c == l - m) v = {0.0, sgn * s2};
  }
  cplx f;
  switch (l & 3) {
    case 0: f = {1.0, 0.0}; break;
    case 1: f = {0.0, -1.0}; break;
    case 2: f = {-1.0, 0.0}; break;
    default: f = {0.0, 1.0}; break;
  }
  return cmul(f, v);
}

// blocks 0..703: transpose weights fp32 [p][u][w] -> bf16 [p][w][u]
// blocks 704..714: Wigner 3j * path-normalization into cgw[p*125 + i*25 + j*5 + k]
// block 715: pack g-metadata GMAP[e] for the 115 (p,i,k) fold entries
__global__ void init_kernel(const float* __restrict__ w, unsigned short* __restrict__ Wt,
                            float* __restrict__ cgw, unsigned int* __restrict__ gmap) {
  const int blk = blockIdx.x;
  const int tid = threadIdx.x;
  if (blk < 704) {
    int g = blk * 256 + tid;                 // 704*256 == 180224 exactly
    int p = g >> 14, rem = g & 16383;
    int u = rem >> 7, wc = rem & 127;
    Wt[(p << 14) + (wc << 7) + u] = f2bf(w[g]);
    return;
  }
  if (blk == 715) {
    if (tid < 115) {
      const int PBt[12] = {0,1,4,9,18,21,36,45,70,85,90,115};
      const int D2t[11] = {1,3,5,1,3,3,5,1,3,5,5};
      const int D3t[11] = {1,3,5,3,1,5,3,5,3,1,5};
      const int O2t[11] = {0,1,4,0,1,1,4,0,1,4,4};
      int p = 0;
      while (tid >= PBt[p + 1]) ++p;
      int le = tid - PBt[p];
      int i = le / D3t[p], k = le % D3t[p];
      gmap[tid] = ((unsigned)(p * 125 + i * 25 + k) << 8) | (O2t[p] << 4) | D2t[p];
    }
    return;
  }
  const int p = blk - 704;
  const int L1t[11] = {0,0,0,1,1,1,1,2,2,2,2};
  const int L2t[11] = {0,1,2,0,1,1,2,0,1,2,2};
  const int L3t[11] = {0,1,2,1,0,2,1,2,1,0,2};
  const double FAN[11] = {384.,512.,512.,512.,384.,512.,512.,512.,512.,384.,512.};
  const int l1 = L1t[p], l2 = L2t[p], l3 = L3t[p];
  const int n1 = 2 * l1 + 1, n2 = 2 * l2 + 1, n3 = 2 * l3 + 1;
  if (tid >= n1 * n2 * n3) return;
  const int a = tid / (n2 * n3), b = (tid / n3) % n2, c = tid % n3;
  double sre = 0.0;
  for (int i = 0; i < n1; ++i)
    for (int k = 0; k < n2; ++k)
      for (int n = 0; n < n3; ++n) {
        double cg = su2_cg(l1, l2, l3, i - l1, k - l2, n - l3);
        if (cg == 0.0) continue;
        cplx q1 = q_entry(l1, i, a);
        cplx q2 = q_entry(l2, k, b);
        cplx q3 = q_entry(l3, n, c);
        q3.im = -q3.im;                      // conj(Q3)
        cplx pr = cmul(cmul(q1, q2), q3);
        sre += pr.re * cg;
      }
  cgw[p * 125 + a * 25 + b * 5 + c] = (float)(sre / sqrt(FAN[p]));
}

// ---------------- main kernel ----------------
// LDS x1 tile: PLANE-MAJOR bf16. 9 planes (l1=0: 1, l1=1: 3, l1=2: 5), each
// 16 rows x 128 u at pitch 132 shorts. Plane pi base = pi*2112 shorts.
// Total 19008 shorts = 38016 B. g_lds[e][row16] f32: 115 x 16 = 7360 B.
__device__ __forceinline__ void stage_all(const float* __restrict__ x1, int Mbase,
                                          unsigned short* __restrict__ s_a) {
  const int tid = threadIdx.x;
#pragma unroll 4
  for (int rep = 0; rep < 18; ++rep) {
    int it = tid + rep * 256;                // 4608 float4-loads total
    int row = it / 288, c4 = it % 288;
    int col = c4 << 2;                       // float4 never straddles groups
    const f32x4 v = __builtin_nontemporal_load(
        (const f32x4*)&x1[(size_t)(Mbase + row) * 1152 + col]);
    unsigned short* sr = s_a + row * 132;
    if (col < 128) {
      u16x4 h;
#pragma unroll
      for (int q = 0; q < 4; ++q) h[q] = f2bf(v[q]);
      *(u16x4*)&sr[col] = h;
    } else if (col < 512) {
      int cc = col - 128;
#pragma unroll
      for (int q = 0; q < 4; ++q) {
        int u = (cc + q) / 3, i = (cc + q) % 3;
        sr[(1 + i) * 2112 + u] = f2bf(v[q]);
      }
    } else {
      int cc = col - 512;
#pragma unroll
      for (int q = 0; q < 4; ++q) {
        int u = (cc + q) / 5, i = (cc + q) % 5;
        sr[(4 + i) * 2112 + u] = f2bf(v[q]);
      }
    }
  }
}

// y_p[b,i,w] = sum_u x1[b,u,i] * W_p[u,w]  (MFMA GEMM per component i), then
// fold acc[k] += g[b,i,k] * y_i. Planes processed in PAIRS: 4 independent
// MFMA chains in flight (R10 had 2 -> latency-bound at 94us-issue/390us-wall).
// Pair loop stays unroll-1 to cap transients (R9 spill lesson).
template<int PID, int L1, int L3, int PBASE>
__device__ __forceinline__ void do_path(const unsigned short* __restrict__ s_a,
                                        const float* __restrict__ g_lds,
                                        const unsigned short* __restrict__ Wt,
                                        int kg, int r16, int nbase,
                                        f32x4 (&acc)[2 * L3 + 1][2]) {
  constexpr int D1 = 2 * L1 + 1, D3 = 2 * L3 + 1;
  constexpr int GB = (L1 == 0) ? 0 : ((L1 == 1) ? 2112 : 8448);
  const unsigned short* __restrict__ wbase = Wt + (PID << 14);
  // all 8 weight frags once per path (32 VGPRs, loaded from L2 once)
  u32x4 bw[2][4];
#pragma unroll
  for (int nf = 0; nf < 2; ++nf)
#pragma unroll
    for (int us = 0; us < 4; ++us)
      bw[nf][us] = *(const u32x4*)&wbase[(nbase + nf * 16 + r16) * 128 + us * 32 + kg * 8];
  const unsigned short* __restrict__ ap0 = s_a + GB + r16 * 132 + kg * 8;
  // ---- plane pairs ----
#pragma unroll 1
  for (int ii = 0; ii + 1 < D1; ii += 2) {
    const unsigned short* apA = ap0 + ii * 2112;
    const unsigned short* apB = apA + 2112;
    f32x4 y0[2] = {f32x4{0.f, 0.f, 0.f, 0.f}, f32x4{0.f, 0.f, 0.f, 0.f}};
    f32x4 y1[2] = {f32x4{0.f, 0.f, 0.f, 0.f}, f32x4{0.f, 0.f, 0.f, 0.f}};
#pragma unroll
    for (int us = 0; us < 4; ++us) {
      const u32x4 a0 = *(const u32x4*)(apA + us * 32);
      const u32x4 a1 = *(const u32x4*)(apB + us * 32);
#pragma unroll
      for (int nf = 0; nf < 2; ++nf) {
        y0[nf] = __builtin_amdgcn_mfma_f32_16x16x32_bf16(
            __builtin_bit_cast(bf16x8, a0), __builtin_bit_cast(bf16x8, bw[nf][us]),
            y0[nf], 0, 0, 0);
        y1[nf] = __builtin_amdgcn_mfma_f32_16x16x32_bf16(
            __builtin_bit_cast(bf16x8, a1), __builtin_bit_cast(bf16x8, bw[nf][us]),
            y1[nf], 0, 0, 0);
      }
    }
#pragma unroll
    for (int k = 0; k < D3; ++k) {
      const f32x4 gA = *(const f32x4*)&g_lds[((PBASE + ii * D3 + k) << 4) + (kg << 2)];
      const f32x4 gB = *(const f32x4*)&g_lds[((PBASE + (ii + 1) * D3 + k) << 4) + (kg << 2)];
#pragma unroll
      for (int nf = 0; nf < 2; ++nf) {
        acc[k][nf] += gA * y0[nf];
        acc[k][nf] += gB * y1[nf];
      }
    }
  }
  // ---- odd tail plane ----
  if (D1 & 1) {
    constexpr int it = D1 - 1;
    const unsigned short* ap = ap0 + it * 2112;
    f32x4 y[2] = {f32x4{0.f, 0.f, 0.f, 0.f}, f32x4{0.f, 0.f, 0.f, 0.f}};
#pragma unroll
    for (int us = 0; us < 4; ++us) {
      const u32x4 af = *(const u32x4*)(ap + us * 32);
#pragma unroll
      for (int nf = 0; nf < 2; ++nf)
        y[nf] = __builtin_amdgcn_mfma_f32_16x16x32_bf16(
            __builtin_bit_cast(bf16x8, af), __builtin_bit_cast(bf16x8, bw[nf][us]),
            y[nf], 0, 0, 0);
    }
#pragma unroll
    for (int k = 0; k < D3; ++k) {
      const f32x4 g4 = *(const f32x4*)&g_lds[((PBASE + it * D3 + k) << 4) + (kg << 2)];
#pragma unroll
      for (int nf = 0; nf < 2; ++nf) acc[k][nf] += g4 * y[nf];
    }
  }
}

__global__ void __launch_bounds__(256, 2) fctp_main(
    const float* __restrict__ x1, const float* __restrict__ x2,
    const float* __restrict__ cgw, const unsigned int* __restrict__ gmap,
    const unsigned short* __restrict__ Wt, float* __restrict__ out) {
  __shared__ __align__(16) unsigned short s_a[19008];  // 38016 B plane-major x1
  __shared__ __align__(16) float g_lds[1840];          // 7360 B g[e][row]
  const int tid = threadIdx.x;
  const int Mbase = blockIdx.x << 4;

  stage_all(x1, Mbase, s_a);

  // cooperative g: g[e][row] = sum_j x2[Mbase+row][o2+j] * cgw[co + j*5]
#pragma unroll 1
  for (int t = tid; t < 1840; t += 256) {
    int row = t & 15, e = t >> 4;
    unsigned m = gmap[e];
    int d2 = m & 15, o2 = (m >> 4) & 15, co = m >> 8;
    const float* xp = x2 + (size_t)(Mbase + row) * 9 + o2;
    const float* cp = cgw + co;
    float s = 0.f;
    for (int j = 0; j < d2; ++j) s += xp[j] * cp[j * 5];
    g_lds[(e << 4) + row] = s;
  }

  const int lane = tid & 63, ni = tid >> 6;
  const int r16 = lane & 15, kg = lane >> 4;
  const int nbase = ni << 5;          // this wave's 32-wide w window

  __syncthreads();                    // x1 planes + g ready

  const int bout = Mbase + (kg << 2);

  // ---- i3 = 0 (cols [0,128), d3=1): paths 0,4,9 ----
  {
    f32x4 acc[1][2] = {};
    do_path<0, 0, 0, 0>(s_a, g_lds, Wt, kg, r16, nbase, acc);
    do_path<4, 1, 0, 18>(s_a, g_lds, Wt, kg, r16, nbase, acc);
    do_path<9, 2, 0, 85>(s_a, g_lds, Wt, kg, r16, nbase, acc);
#pragma unroll
    for (int nf = 0; nf < 2; ++nf) {
      const int w = nbase + nf * 16 + r16;
#pragma unroll
      for (int r = 0; r < 4; ++r)
        __builtin_nontemporal_store(acc[0][nf][r],
                                    &out[(size_t)(bout + r) * 1152 + w]);
    }
  }
  // ---- i3 = 1 (cols 128 + w*3 + k, d3=3): paths 1,3,6,8 ----
  {
    f32x4 acc[3][2] = {};
    do_path<1, 0, 1, 1>(s_a, g_lds, Wt, kg, r16, nbase, acc);
    do_path<3, 1, 1, 9>(s_a, g_lds, Wt, kg, r16, nbase, acc);
    do_path<6, 1, 1, 36>(s_a, g_lds, Wt, kg, r16, nbase, acc);
    do_path<8, 2, 1, 70>(s_a, g_lds, Wt, kg, r16, nbase, acc);
#pragma unroll
    for (int nf = 0; nf < 2; ++nf) {
      const int w = nbase + nf * 16 + r16;
#pragma unroll
      for (int r = 0; r < 4; ++r) {
        float* o = out + (size_t)(bout + r) * 1152 + 128 + w * 3;
#pragma unroll
        for (int k = 0; k < 3; ++k) o[k] = acc[k][nf][r];
      }
    }
  }
  // ---- i3 = 2 (cols 512 + w*5 + k, d3=5): paths 2,5,7,10 ----
  {
    f32x4 acc[5][2] = {};
    do_path<2, 0, 2, 4>(s_a, g_lds, Wt, kg, r16, nbase, acc);
    do_path<5, 1, 2, 21>(s_a, g_lds, Wt, kg, r16, nbase, acc);
    do_path<7, 2, 2, 45>(s_a, g_lds, Wt, kg, r16, nbase, acc);
    do_path<10, 2, 2, 90>(s_a, g_lds, Wt, kg, r16, nbase, acc);
#pragma unroll
    for (int nf = 0; nf < 2; ++nf) {
      const int w = nbase + nf * 16 + r16;
#pragma unroll
      for (int r = 0; r < 4; ++r) {
        float* o = out + (size_t)(bout + r) * 1152 + 512 + w * 5;
#pragma unroll
        for (int k = 0; k < 5; ++k) o[k] = acc[k][nf][r];
      }
    }
  }
}

extern "C" void kernel_launch(void* const* d_in, const int* in_sizes, int n_in,
                              void* d_out, int out_size, void* d_ws, size_t ws_size,
                              hipStream_t stream) {
  (void)in_sizes; (void)n_in; (void)out_size; (void)ws_size;
  const float* x1 = (const float*)d_in[0];
  const float* x2 = (const float*)d_in[1];
  const float* w  = (const float*)d_in[2];
  float* out = (float*)d_out;
  float* cgw = (float*)d_ws;                                     // 1375 floats
  unsigned int* gmap = (unsigned int*)((char*)d_ws + 5504);      // 115 u32
  unsigned short* Wt = (unsigned short*)((char*)d_ws + 8192);    // 11*128*128 bf16
  init_kernel<<<dim3(716), dim3(256), 0, stream>>>(w, Wt, cgw, gmap);
  fctp_main<<<dim3(4096), dim3(256), 0, stream>>>(x1, x2, cgw, gmap, Wt, out);
}